// Round 6
// baseline (809.007 us; speedup 1.0000x reference)
//
#include <hip/hip_runtime.h>
#include <hip/hip_bf16.h>

typedef __hip_bfloat16 bf16;

#define BB 4
#define HH 240
#define WW 320
#define CG 64
#define NCO 24
#define HWSZ (HH*WW)

// Runtime-polymorphic input load (compile-time flavor via template).
template<int ISBF>
__device__ __forceinline__ float ldT(const void* __restrict__ p, long i) {
    if (ISBF) return __bfloat162float(((const bf16*)p)[i]);
    return ((const float*)p)[i];
}

__device__ __forceinline__ float ldF(const void* __restrict__ p, long i, int isbf) {
    if (isbf) return __bfloat162float(((const bf16*)p)[i]);
    return ((const float*)p)[i];
}

__device__ __forceinline__ int detect_bf16(const void* asc) {
    // aff_scale_const == 4.0f. fp32 LE low uint16 of 0x40800000 is 0x0000;
    // bf16 encoding of 4.0 is 0x4080. Nonzero => bf16 inputs.
    return ((const unsigned short*)asc)[0] != 0;
}

// ---------------------------------------------------------------------------
// Kernel 1: bilinear 2x upsample (jax.image.resize == clamped bilinear at
// src = 0.5*o - 0.25), input -> fp32 ws [b][c][i][j]
// ---------------------------------------------------------------------------
__global__ __launch_bounds__(256) void upsample_kernel(const void* __restrict__ tin,
                                                       const void* __restrict__ asc,
                                                       float* __restrict__ fea) {
    int isbf = detect_bf16(asc);
    int idx = blockIdx.x * 256 + threadIdx.x;
    if (idx >= BB * 8 * HWSZ) return;
    int j = idx % WW;
    int rest = idx / WW;
    int i = rest % HH;
    int bc = rest / HH;  // b*8+c
    float sy = 0.5f * (float)i - 0.25f;
    float sx = 0.5f * (float)j - 0.25f;
    float y0f = floorf(sy), x0f = floorf(sx);
    float wy = sy - y0f, wx = sx - x0f;
    int y0 = (int)y0f, x0 = (int)x0f;
    int y0c = min(max(y0, 0), 119), y1c = min(max(y0 + 1, 0), 119);
    int x0c = min(max(x0, 0), 159), x1c = min(max(x0 + 1, 0), 159);
    long base = (long)bc * 120 * 160;
    float v00 = ldF(tin, base + y0c * 160 + x0c, isbf);
    float v01 = ldF(tin, base + y0c * 160 + x1c, isbf);
    float v10 = ldF(tin, base + y1c * 160 + x0c, isbf);
    float v11 = ldF(tin, base + y1c * 160 + x1c, isbf);
    fea[idx] = (1.f - wy) * ((1.f - wx) * v00 + wx * v01)
             + wy * ((1.f - wx) * v10 + wx * v11);
}

// ---------------------------------------------------------------------------
// Kernel 2: 3x3 conv 64->24 + bias, pad 1. Output pixel-major fp32:
// oa[((b*H+i)*W+j)*24 + c].
//
// R5 post-mortem: 1 px/thread made weight ds_read:FMA 1:1 (13824 ds/wave)
// -> LDS-pipe co-bottleneck, VALUBusy 60% at 421us. R6: 2 px/thread +
// float4-vectorized weight reads (stride-12 LDS layout, wave-uniform
// broadcast => conflict-free): 3 ds per (cc,co) feeding 18 FMAs. Tile
// 32x16, 600 blocks (2.34/CU) keeps the grid balanced.
// ---------------------------------------------------------------------------
template<int ISBF>
__device__ __forceinline__ void conv_body(const void* __restrict__ g,
                                          const void* __restrict__ w,
                                          const void* __restrict__ bias,
                                          float* __restrict__ oa) {
    const int b = blockIdx.z;
    const int i0 = blockIdx.y * 16;
    const int j0 = blockIdx.x * 32;
    const int tx = threadIdx.x & 15;   // pair-column 0..15 -> px cols 2tx,2tx+1
    const int ty = threadIdx.x >> 4;   // row 0..15

    __shared__ float gl[8][18][34];    // 8 in-ch chunk, rows 18, cols 32+2 halo
    __shared__ float wl[8][NCO][12];   // stride 12 -> 48B, 16B-aligned float4 reads

    float acc0[NCO], acc1[NCO];
#pragma unroll
    for (int c = 0; c < NCO; c++) {
        float bv = ldT<ISBF>(bias, c);
        acc0[c] = bv; acc1[c] = bv;
    }

    for (int ci0 = 0; ci0 < CG; ci0 += 8) {
        __syncthreads();
        // stage weight slice (1728 scalars)
        for (int idx = threadIdx.x; idx < 8 * NCO * 9; idx += 256) {
            int t = idx % 9;
            int rest = idx / 9;
            int cc = rest & 7;
            int co = rest >> 3;
            wl[cc][co][t] = ldT<ISBF>(w, (long)(co * CG + ci0 + cc) * 9 + t);
        }
        // stage guidance tile with halo (zero padded): 8*18*34 = 4896
        for (int idx = threadIdx.x; idx < 8 * 18 * 34; idx += 256) {
            int cc = idx / 612;
            int rem = idx - cc * 612;
            int r = rem / 34;
            int c2 = rem - r * 34;
            int gi = i0 - 1 + r;
            int gj = j0 - 1 + c2;
            float v = 0.f;
            if (gi >= 0 && gi < HH && gj >= 0 && gj < WW)
                v = ldT<ISBF>(g, ((long)(b * CG + ci0 + cc) * HH + gi) * WW + gj);
            gl[cc][r][c2] = v;
        }
        __syncthreads();

        for (int cc = 0; cc < 8; cc++) {
            // activation window: 3 rows x 4 cols (cols 2tx .. 2tx+3 in halo space)
            float ga[12];
#pragma unroll
            for (int dy = 0; dy < 3; dy++) {
                float2 p0 = *(const float2*)&gl[cc][ty + dy][2 * tx];
                float2 p1 = *(const float2*)&gl[cc][ty + dy][2 * tx + 2];
                ga[dy * 4 + 0] = p0.x; ga[dy * 4 + 1] = p0.y;
                ga[dy * 4 + 2] = p1.x; ga[dy * 4 + 3] = p1.y;
            }
#pragma unroll 3
            for (int co = 0; co < NCO; co++) {
                float4 w0 = *(const float4*)&wl[cc][co][0];
                float4 w1 = *(const float4*)&wl[cc][co][4];
                float w8 = wl[cc][co][8];
                float wv[9] = {w0.x, w0.y, w0.z, w0.w, w1.x, w1.y, w1.z, w1.w, w8};
                float s0 = 0.f, s1 = 0.f;
#pragma unroll
                for (int dy = 0; dy < 3; dy++)
#pragma unroll
                    for (int dx = 0; dx < 3; dx++) {
                        float wq = wv[dy * 3 + dx];
                        s0 += wq * ga[dy * 4 + dx];
                        s1 += wq * ga[dy * 4 + dx + 1];
                    }
                acc0[co] += s0;
                acc1[co] += s1;
            }
        }
    }
    int i = i0 + ty;
    int j = j0 + 2 * tx;
    float4* p0 = (float4*)&oa[(((size_t)b * HH + i) * WW + j) * NCO];
    float4* p1 = (float4*)&oa[(((size_t)b * HH + i) * WW + j + 1) * NCO];
#pragma unroll
    for (int q = 0; q < 6; q++) {
        p0[q] = make_float4(acc0[4 * q], acc0[4 * q + 1], acc0[4 * q + 2], acc0[4 * q + 3]);
        p1[q] = make_float4(acc1[4 * q], acc1[4 * q + 1], acc1[4 * q + 2], acc1[4 * q + 3]);
    }
}

__global__ __launch_bounds__(256, 3) void conv_kernel(const void* __restrict__ g,
                                                      const void* __restrict__ w,
                                                      const void* __restrict__ bias,
                                                      const void* __restrict__ asc,
                                                      float* __restrict__ oa) {
    if (detect_bf16(asc)) conv_body<1>(g, w, bias, oa);
    else                  conv_body<0>(g, w, bias, oa);
}

// ---------------------------------------------------------------------------
// bilinear with zero padding outside (reference _bilinear_zeros semantics)
// ---------------------------------------------------------------------------
__device__ __forceinline__ float bil_zero_f32(const float* __restrict__ img,
                                              float x, float y, int Hh, int Wwd) {
    float x0f = floorf(x), y0f = floorf(y);
    float wx = x - x0f, wy = y - y0f;
    int x0 = (int)x0f, y0 = (int)y0f;
    float v00 = 0.f, v01 = 0.f, v10 = 0.f, v11 = 0.f;
    bool xv0 = (x0 >= 0) && (x0 < Wwd);
    bool xv1 = (x0 + 1 >= 0) && (x0 + 1 < Wwd);
    if (y0 >= 0 && y0 < Hh) {
        const float* r = img + (size_t)y0 * Wwd;
        if (xv0) v00 = r[x0];
        if (xv1) v01 = r[x0 + 1];
    }
    if (y0 + 1 >= 0 && y0 + 1 < Hh) {
        const float* r = img + (size_t)(y0 + 1) * Wwd;
        if (xv0) v10 = r[x0];
        if (xv1) v11 = r[x0 + 1];
    }
    return (1.f - wy) * ((1.f - wx) * v00 + wx * v01)
         + wy * ((1.f - wx) * v10 + wx * v11);
}

__device__ __forceinline__ float bil_zero_poly(const void* __restrict__ img, long base,
                                               float x, float y, int Hh, int Wwd, int isbf) {
    float x0f = floorf(x), y0f = floorf(y);
    float wx = x - x0f, wy = y - y0f;
    int x0 = (int)x0f, y0 = (int)y0f;
    float v00 = 0.f, v01 = 0.f, v10 = 0.f, v11 = 0.f;
    bool xv0 = (x0 >= 0) && (x0 < Wwd);
    bool xv1 = (x0 + 1 >= 0) && (x0 + 1 < Wwd);
    if (y0 >= 0 && y0 < Hh) {
        long r = base + (long)y0 * Wwd;
        if (xv0) v00 = ldF(img, r + x0, isbf);
        if (xv1) v01 = ldF(img, r + x0 + 1, isbf);
    }
    if (y0 + 1 >= 0 && y0 + 1 < Hh) {
        long r = base + (long)(y0 + 1) * Wwd;
        if (xv0) v10 = ldF(img, r + x0, isbf);
        if (xv1) v11 = ldF(img, r + x0 + 1, isbf);
    }
    return (1.f - wy) * ((1.f - wx) * v00 + wx * v01)
         + wy * ((1.f - wx) * v10 + wx * v11);
}

// ---------------------------------------------------------------------------
// Kernel 3: scrambled cosine-affinity gather + conf + TGASS + softmax + writes.
//   cos_w[b,c,i,j] = sum_{n<8} fea_up[b,n,i,j] * bil(fea_up[b, i/30], px, py)
//   source grid pixel (pi,qj) = ((i%30)*8 + j/40, (j%40)*8 + n)
//   px = oa[pi,qj,2c] + add, py = oa[pi,qj,2c+1] + add, add = (c<4 ? pi : qj)
// Outputs fp32 (reference dtype).
// ---------------------------------------------------------------------------
__global__ __launch_bounds__(256) void final_kernel(const float* __restrict__ oa,
                                                    const float* __restrict__ fea,
                                                    const void* __restrict__ conf_in,
                                                    const void* __restrict__ asc_p,
                                                    float* __restrict__ out) {
    int isbf = detect_bf16(asc_p);
    int idx = blockIdx.x * 256 + threadIdx.x;
    if (idx >= BB * HWSZ) return;
    int j = idx % WW;
    int rest = idx / WW;
    int i = rest % HH;
    int b = rest / HH;

    const float* feaB = fea + (size_t)b * 8 * HWSZ;
    float f[8];
#pragma unroll
    for (int n = 0; n < 8; n++)
        f[n] = feaB[(size_t)n * HWSZ + (size_t)i * WW + j];

    int c_img = i / 30;
    int pi = (i % 30) * 8 + j / 40;
    int pj0 = (j % 40) * 8;
    const float* feaC = feaB + (size_t)c_img * HWSZ;

    float cos_acc[8];
#pragma unroll
    for (int c = 0; c < 8; c++) cos_acc[c] = 0.f;

#pragma unroll
    for (int n = 0; n < 8; n++) {
        int qj = pj0 + n;
        const float4* oq = (const float4*)&oa[(((size_t)b * HH + pi) * WW + qj) * NCO];
        float4 o0 = oq[0], o1 = oq[1], o2 = oq[2], o3 = oq[3];
        float off[16] = {o0.x, o0.y, o0.z, o0.w, o1.x, o1.y, o1.z, o1.w,
                         o2.x, o2.y, o2.z, o2.w, o3.x, o3.y, o3.z, o3.w};
        float fn = f[n];
#pragma unroll
        for (int c = 0; c < 8; c++) {
            float add = (c < 4) ? (float)pi : (float)qj;
            float px = off[2 * c] + add;
            float py = off[2 * c + 1] + add;
            cos_acc[c] += fn * bil_zero_f32(feaC, px, py, HH, WW);
        }
    }

    const float4* op = (const float4*)&oa[(((size_t)b * HH + i) * WW + j) * NCO];
    float own[24];
#pragma unroll
    for (int q = 0; q < 6; q++) {
        float4 v = op[q];
        own[4 * q] = v.x; own[4 * q + 1] = v.y; own[4 * q + 2] = v.z; own[4 * q + 3] = v.w;
    }

    float asc = ldF(asc_p, 0, isbf) + 1e-8f;
    long cbase = (long)b * HWSZ;

    float a[8];
    float ssum = 0.f;
#pragma unroll
    for (int c = 0; c < 8; c++) {
        float v = own[16 + c] * cos_acc[c];
        v = tanhf(v) / asc;
        float py2 = own[2 * c] + (float)i;       // channel 0 = dy
        float px2 = own[2 * c + 1] + (float)j;   // channel 1 = dx
        float cf = bil_zero_poly(conf_in, cbase, px2, py2, HH, WW, isbf);
        v *= cf;
        a[c] = v;
        ssum += fabsf(v);
    }
    ssum += 1e-4f;
    ssum = fmaxf(ssum, 1.0f);
    float inv = 1.0f / ssum;
    float asum = 0.f;
#pragma unroll
    for (int c = 0; c < 8; c++) { a[c] *= inv; asum += a[c]; }
    float aref = 1.0f - asum;

    float vals[9];
#pragma unroll
    for (int c = 0; c < 4; c++) vals[c] = a[c];
    vals[4] = aref;
#pragma unroll
    for (int c = 4; c < 8; c++) vals[c + 1] = a[c];
    float m = vals[0];
#pragma unroll
    for (int k = 1; k < 9; k++) m = fmaxf(m, vals[k]);
    float es = 0.f;
#pragma unroll
    for (int k = 0; k < 9; k++) { vals[k] = __expf(vals[k] - m); es += vals[k]; }
    float ei = 1.0f / es;

    size_t pix = (size_t)i * WW + j;
    size_t base_o = (size_t)b * 18 * HWSZ + pix;
#pragma unroll
    for (int ch = 0; ch < 18; ch++) {
        float v;
        if (ch < 8) v = own[ch];
        else if (ch < 10) v = 0.f;
        else v = own[ch - 2];
        out[base_o + (size_t)ch * HWSZ] = v;
    }
    float* aff_out = out + (size_t)BB * 18 * HWSZ;
    size_t base_a = (size_t)b * 9 * HWSZ + pix;
#pragma unroll
    for (int k = 0; k < 9; k++)
        aff_out[base_a + (size_t)k * HWSZ] = vals[k] * ei;
}

// ---------------------------------------------------------------------------
extern "C" void kernel_launch(void* const* d_in, const int* in_sizes, int n_in,
                              void* d_out, int out_size, void* d_ws, size_t ws_size,
                              hipStream_t stream) {
    const void* guidance = d_in[0];
    const void* gtconf   = d_in[1];
    const void* tgt      = d_in[2];
    const void* conv_w   = d_in[3];
    const void* conv_b   = d_in[4];
    const void* asc      = d_in[5];

    float* oa  = (float*)d_ws;                        // B*H*W*24 fp32
    float* fea = oa + (size_t)BB * HWSZ * NCO;        // B*8*H*W fp32
    float* out = (float*)d_out;

    int n_up = BB * 8 * HWSZ;
    upsample_kernel<<<(n_up + 255) / 256, 256, 0, stream>>>(tgt, asc, fea);

    dim3 cgrid(WW / 32, HH / 16, BB);
    conv_kernel<<<cgrid, 256, 0, stream>>>(guidance, conv_w, conv_b, asc, oa);

    int n_fin = BB * HWSZ;
    final_kernel<<<(n_fin + 255) / 256, 256, 0, stream>>>(oa, fea, gtconf, asc, out);
}

// Round 7
// 413.196 us; speedup vs baseline: 1.9579x; 1.9579x over previous
//
#include <hip/hip_runtime.h>
#include <hip/hip_bf16.h>

typedef __hip_bfloat16 bf16;
typedef __bf16 bf16x8 __attribute__((ext_vector_type(8)));
typedef float f32x4 __attribute__((ext_vector_type(4)));

#define BB 4
#define HH 240
#define WW 320
#define CG 64
#define NCO 24
#define HWSZ (HH*WW)

__device__ __forceinline__ float ldF(const void* __restrict__ p, long i, int isbf) {
    if (isbf) return __bfloat162float(((const bf16*)p)[i]);
    return ((const float*)p)[i];
}

__device__ __forceinline__ int detect_bf16(const void* asc) {
    // aff_scale_const == 4.0f: fp32 LE low u16 = 0x0000, bf16 = 0x4080.
    return ((const unsigned short*)asc)[0] != 0;
}

__device__ __forceinline__ unsigned short f2bfbits(float v) {
    bf16 h = __float2bfloat16(v);
    return *(unsigned short*)&h;
}

// ---------------------------------------------------------------------------
// Kernel 1: bilinear 2x upsample -> fp32 ws [b][c][i][j]
// ---------------------------------------------------------------------------
__global__ __launch_bounds__(256) void upsample_kernel(const void* __restrict__ tin,
                                                       const void* __restrict__ asc,
                                                       float* __restrict__ fea) {
    int isbf = detect_bf16(asc);
    int idx = blockIdx.x * 256 + threadIdx.x;
    if (idx >= BB * 8 * HWSZ) return;
    int j = idx % WW;
    int rest = idx / WW;
    int i = rest % HH;
    int bc = rest / HH;
    float sy = 0.5f * (float)i - 0.25f;
    float sx = 0.5f * (float)j - 0.25f;
    float y0f = floorf(sy), x0f = floorf(sx);
    float wy = sy - y0f, wx = sx - x0f;
    int y0 = (int)y0f, x0 = (int)x0f;
    int y0c = min(max(y0, 0), 119), y1c = min(max(y0 + 1, 0), 119);
    int x0c = min(max(x0, 0), 159), x1c = min(max(x0 + 1, 0), 159);
    long base = (long)bc * 120 * 160;
    float v00 = ldF(tin, base + y0c * 160 + x0c, isbf);
    float v01 = ldF(tin, base + y0c * 160 + x1c, isbf);
    float v10 = ldF(tin, base + y1c * 160 + x0c, isbf);
    float v11 = ldF(tin, base + y1c * 160 + x1c, isbf);
    fea[idx] = (1.f - wy) * ((1.f - wx) * v00 + wx * v01)
             + wy * ((1.f - wx) * v10 + wx * v11);
}

// ---------------------------------------------------------------------------
// Prep A: guidance NCHW -> channels-last bf16 gT[b][y][x][ci] via LDS transpose
// grid (5, 240, 4): 64-px row chunk per block.
// ---------------------------------------------------------------------------
__global__ __launch_bounds__(256) void prep_guidance(const void* __restrict__ g,
                                                     const void* __restrict__ asc,
                                                     unsigned short* __restrict__ gTu) {
    int isbf = detect_bf16(asc);
    int x0 = blockIdx.x * 64;
    int y  = blockIdx.y;
    int b  = blockIdx.z;
    __shared__ unsigned short sh[64][66];
    int tid = threadIdx.x;
#pragma unroll
    for (int it = 0; it < 16; it++) {
        int idx = it * 256 + tid;
        int ci = idx >> 6;
        int xg = idx & 63;
        float v = ldF(g, ((long)(b * CG + ci) * HH + y) * WW + x0 + xg, isbf);
        sh[xg][ci] = f2bfbits(v);
    }
    __syncthreads();
#pragma unroll
    for (int it = 0; it < 16; it++) {
        int idx = it * 256 + tid;
        int xg = idx >> 6;
        int ci = idx & 63;
        gTu[((((long)b * HH + y) * WW + x0 + xg) << 6) + ci] = sh[xg][ci];
    }
}

// ---------------------------------------------------------------------------
// Prep B: weights -> MFMA B-fragment layout Bp[t][n(32, 24 real)][k'(32)] bf16
// t = tap*2 + cihalf, k' = ci_local, tap = dy*3+dx.
// ---------------------------------------------------------------------------
__global__ __launch_bounds__(256) void prep_weights(const void* __restrict__ w,
                                                    const void* __restrict__ asc,
                                                    unsigned short* __restrict__ Bpu) {
    int isbf = detect_bf16(asc);
    for (int idx = threadIdx.x; idx < 18 * 32 * 32; idx += 256) {
        int t = idx >> 10;
        int r = idx & 1023;
        int n = r >> 5;
        int k = r & 31;
        int tap = t >> 1;
        int ch = t & 1;
        float v = 0.f;
        if (n < NCO)
            v = ldF(w, ((long)n * CG + ch * 32 + k) * 9 + tap, isbf);
        Bpu[idx] = f2bfbits(v);
    }
}

// ---------------------------------------------------------------------------
// Kernel 2 (MFMA): im2col GEMM conv. One wave = 16 px x 24(pad 32) co, K=576.
// K-step = (tap, cihalf): A-frag = 16B contiguous ci from gT at the shifted
// pixel; B-frag = 16B from Bp. No LDS, no barriers.
// Layouts (m89/m120-verified): A[m=lane&15][k=quad*8+j],
// B[k=quad*8+j][n=lane&15], D: row(m)=quad*4+reg, col(n)=lane&15.
// ---------------------------------------------------------------------------
__global__ __launch_bounds__(256) void conv_mfma_kernel(const unsigned short* __restrict__ gTu,
                                                        const unsigned short* __restrict__ Bpu,
                                                        const void* __restrict__ bias,
                                                        const void* __restrict__ asc,
                                                        float* __restrict__ oa) {
    int isbf = detect_bf16(asc);
    int y  = blockIdx.y;
    int b  = blockIdx.z;
    int wid  = threadIdx.x >> 6;
    int lane = threadIdx.x & 63;
    int m = lane & 15, quad = lane >> 4;
    int x0 = blockIdx.x * 64 + wid * 16;

    f32x4 acc0 = {0.f, 0.f, 0.f, 0.f};
    f32x4 acc1 = {0.f, 0.f, 0.f, 0.f};

    for (int tap = 0; tap < 9; tap++) {
        int yy = y + tap / 3 - 1;
        if (yy < 0 || yy >= HH) continue;          // wave-uniform skip
        int xx = x0 + m + (tap % 3) - 1;
        bool xok = (xx >= 0) && (xx < WW);
        int xcl = min(max(xx, 0), WW - 1);
        long abase = (((long)b * HH + yy) * WW + xcl) * 64;
#pragma unroll
        for (int ch = 0; ch < 2; ch++) {
            int t = tap * 2 + ch;
            int4 ai = *(const int4*)(gTu + abase + ch * 32 + quad * 8);
            if (!xok) { ai.x = 0; ai.y = 0; ai.z = 0; ai.w = 0; }
            bf16x8 af = __builtin_bit_cast(bf16x8, ai);
            int4 b0i = *(const int4*)(Bpu + ((t * 32 + m) * 32 + quad * 8));
            int4 b1i = *(const int4*)(Bpu + ((t * 32 + 16 + m) * 32 + quad * 8));
            bf16x8 bf0 = __builtin_bit_cast(bf16x8, b0i);
            bf16x8 bf1 = __builtin_bit_cast(bf16x8, b1i);
            acc0 = __builtin_amdgcn_mfma_f32_16x16x32_bf16(af, bf0, acc0, 0, 0, 0);
            acc1 = __builtin_amdgcn_mfma_f32_16x16x32_bf16(af, bf1, acc1, 0, 0, 0);
        }
    }

    int n = lane & 15;
    float bias0 = ldF(bias, n, isbf);
    float bias1 = (n < 8) ? ldF(bias, 16 + n, isbf) : 0.f;
#pragma unroll
    for (int r = 0; r < 4; r++) {
        int px = x0 + quad * 4 + r;
        float* dst = &oa[(((size_t)b * HH + y) * WW + px) * NCO];
        dst[n] = acc0[r] + bias0;
        if (n < 8) dst[16 + n] = acc1[r] + bias1;
    }
}

// ---------------------------------------------------------------------------
// Fallback scalar conv (used only if ws too small for gT/Bp). Single LDS
// instance (runtime isbf -> one instantiation; fixes the R4-R6 LDS doubling).
// ---------------------------------------------------------------------------
__global__ __launch_bounds__(256, 4) void conv_fallback(const void* __restrict__ g,
                                                        const void* __restrict__ w,
                                                        const void* __restrict__ bias,
                                                        const void* __restrict__ asc,
                                                        float* __restrict__ oa) {
    int isbf = detect_bf16(asc);
    const int b = blockIdx.z;
    const int i0 = blockIdx.y * 16;
    const int j0 = blockIdx.x * 16;
    const int tx = threadIdx.x & 15;
    const int ty = threadIdx.x >> 4;

    __shared__ float gl[8][18][20];
    __shared__ float wl[8][NCO][10];

    float acc[NCO];
#pragma unroll
    for (int c = 0; c < NCO; c++) acc[c] = ldF(bias, c, isbf);

    for (int ci0 = 0; ci0 < CG; ci0 += 8) {
        __syncthreads();
        for (int idx = threadIdx.x; idx < 8 * NCO * 9; idx += 256) {
            int t = idx % 9;
            int rest = idx / 9;
            int cc = rest & 7;
            int co = rest >> 3;
            wl[cc][co][t] = ldF(w, (long)(co * CG + ci0 + cc) * 9 + t, isbf);
        }
        for (int idx = threadIdx.x; idx < 8 * 18 * 18; idx += 256) {
            int cc = idx / 324;
            int rem = idx - cc * 324;
            int r = rem / 18;
            int c2 = rem - r * 18;
            int gi = i0 - 1 + r;
            int gj = j0 - 1 + c2;
            float v = 0.f;
            if (gi >= 0 && gi < HH && gj >= 0 && gj < WW)
                v = ldF(g, ((long)(b * CG + ci0 + cc) * HH + gi) * WW + gj, isbf);
            gl[cc][r][c2] = v;
        }
        __syncthreads();
#pragma unroll
        for (int cc = 0; cc < 8; cc++) {
            float ga[9];
#pragma unroll
            for (int dy = 0; dy < 3; dy++)
#pragma unroll
                for (int dx = 0; dx < 3; dx++)
                    ga[dy * 3 + dx] = gl[cc][ty + dy][tx + dx];
#pragma unroll 4
            for (int co = 0; co < NCO; co++) {
                float s = 0.f;
#pragma unroll
                for (int t = 0; t < 9; t++)
                    s += wl[cc][co][t] * ga[t];
                acc[co] += s;
            }
        }
    }
    int i = i0 + ty, j = j0 + tx;
    float4* p = (float4*)&oa[(((size_t)b * HH + i) * WW + j) * NCO];
#pragma unroll
    for (int q = 0; q < 6; q++)
        p[q] = make_float4(acc[4 * q], acc[4 * q + 1], acc[4 * q + 2], acc[4 * q + 3]);
}

// ---------------------------------------------------------------------------
// bilinear with zero padding outside (reference _bilinear_zeros semantics)
// ---------------------------------------------------------------------------
__device__ __forceinline__ float bil_zero_f32(const float* __restrict__ img,
                                              float x, float y, int Hh, int Wwd) {
    float x0f = floorf(x), y0f = floorf(y);
    float wx = x - x0f, wy = y - y0f;
    int x0 = (int)x0f, y0 = (int)y0f;
    float v00 = 0.f, v01 = 0.f, v10 = 0.f, v11 = 0.f;
    bool xv0 = (x0 >= 0) && (x0 < Wwd);
    bool xv1 = (x0 + 1 >= 0) && (x0 + 1 < Wwd);
    if (y0 >= 0 && y0 < Hh) {
        const float* r = img + (size_t)y0 * Wwd;
        if (xv0) v00 = r[x0];
        if (xv1) v01 = r[x0 + 1];
    }
    if (y0 + 1 >= 0 && y0 + 1 < Hh) {
        const float* r = img + (size_t)(y0 + 1) * Wwd;
        if (xv0) v10 = r[x0];
        if (xv1) v11 = r[x0 + 1];
    }
    return (1.f - wy) * ((1.f - wx) * v00 + wx * v01)
         + wy * ((1.f - wx) * v10 + wx * v11);
}

__device__ __forceinline__ float bil_zero_poly(const void* __restrict__ img, long base,
                                               float x, float y, int Hh, int Wwd, int isbf) {
    float x0f = floorf(x), y0f = floorf(y);
    float wx = x - x0f, wy = y - y0f;
    int x0 = (int)x0f, y0 = (int)y0f;
    float v00 = 0.f, v01 = 0.f, v10 = 0.f, v11 = 0.f;
    bool xv0 = (x0 >= 0) && (x0 < Wwd);
    bool xv1 = (x0 + 1 >= 0) && (x0 + 1 < Wwd);
    if (y0 >= 0 && y0 < Hh) {
        long r = base + (long)y0 * Wwd;
        if (xv0) v00 = ldF(img, r + x0, isbf);
        if (xv1) v01 = ldF(img, r + x0 + 1, isbf);
    }
    if (y0 + 1 >= 0 && y0 + 1 < Hh) {
        long r = base + (long)(y0 + 1) * Wwd;
        if (xv0) v10 = ldF(img, r + x0, isbf);
        if (xv1) v11 = ldF(img, r + x0 + 1, isbf);
    }
    return (1.f - wy) * ((1.f - wx) * v00 + wx * v01)
         + wy * ((1.f - wx) * v10 + wx * v11);
}

// ---------------------------------------------------------------------------
// Kernel 3: scrambled cosine-affinity gather + conf + TGASS + softmax + writes.
//   cos_w[b,c,i,j] = sum_{n<8} fea_up[b,n,i,j] * bil(fea_up[b, i/30], px, py)
//   source grid pixel (pi,qj) = ((i%30)*8 + j/40, (j%40)*8 + n)
//   px = oa[pi,qj,2c] + add, py = oa[pi,qj,2c+1] + add, add = (c<4 ? pi : qj)
// ---------------------------------------------------------------------------
__global__ __launch_bounds__(256) void final_kernel(const float* __restrict__ oa,
                                                    const float* __restrict__ fea,
                                                    const void* __restrict__ conf_in,
                                                    const void* __restrict__ asc_p,
                                                    float* __restrict__ out) {
    int isbf = detect_bf16(asc_p);
    int idx = blockIdx.x * 256 + threadIdx.x;
    if (idx >= BB * HWSZ) return;
    int j = idx % WW;
    int rest = idx / WW;
    int i = rest % HH;
    int b = rest / HH;

    const float* feaB = fea + (size_t)b * 8 * HWSZ;
    float f[8];
#pragma unroll
    for (int n = 0; n < 8; n++)
        f[n] = feaB[(size_t)n * HWSZ + (size_t)i * WW + j];

    int c_img = i / 30;
    int pi = (i % 30) * 8 + j / 40;
    int pj0 = (j % 40) * 8;
    const float* feaC = feaB + (size_t)c_img * HWSZ;

    float cos_acc[8];
#pragma unroll
    for (int c = 0; c < 8; c++) cos_acc[c] = 0.f;

#pragma unroll
    for (int n = 0; n < 8; n++) {
        int qj = pj0 + n;
        const float4* oq = (const float4*)&oa[(((size_t)b * HH + pi) * WW + qj) * NCO];
        float4 o0 = oq[0], o1 = oq[1], o2 = oq[2], o3 = oq[3];
        float off[16] = {o0.x, o0.y, o0.z, o0.w, o1.x, o1.y, o1.z, o1.w,
                         o2.x, o2.y, o2.z, o2.w, o3.x, o3.y, o3.z, o3.w};
        float fn = f[n];
#pragma unroll
        for (int c = 0; c < 8; c++) {
            float add = (c < 4) ? (float)pi : (float)qj;
            float px = off[2 * c] + add;
            float py = off[2 * c + 1] + add;
            cos_acc[c] += fn * bil_zero_f32(feaC, px, py, HH, WW);
        }
    }

    const float4* op = (const float4*)&oa[(((size_t)b * HH + i) * WW + j) * NCO];
    float own[24];
#pragma unroll
    for (int q = 0; q < 6; q++) {
        float4 v = op[q];
        own[4 * q] = v.x; own[4 * q + 1] = v.y; own[4 * q + 2] = v.z; own[4 * q + 3] = v.w;
    }

    float asc = ldF(asc_p, 0, isbf) + 1e-8f;
    long cbase = (long)b * HWSZ;

    float a[8];
    float ssum = 0.f;
#pragma unroll
    for (int c = 0; c < 8; c++) {
        float v = own[16 + c] * cos_acc[c];
        v = tanhf(v) / asc;
        float py2 = own[2 * c] + (float)i;
        float px2 = own[2 * c + 1] + (float)j;
        float cf = bil_zero_poly(conf_in, cbase, px2, py2, HH, WW, isbf);
        v *= cf;
        a[c] = v;
        ssum += fabsf(v);
    }
    ssum += 1e-4f;
    ssum = fmaxf(ssum, 1.0f);
    float inv = 1.0f / ssum;
    float asum = 0.f;
#pragma unroll
    for (int c = 0; c < 8; c++) { a[c] *= inv; asum += a[c]; }
    float aref = 1.0f - asum;

    float vals[9];
#pragma unroll
    for (int c = 0; c < 4; c++) vals[c] = a[c];
    vals[4] = aref;
#pragma unroll
    for (int c = 4; c < 8; c++) vals[c + 1] = a[c];
    float m = vals[0];
#pragma unroll
    for (int k = 1; k < 9; k++) m = fmaxf(m, vals[k]);
    float es = 0.f;
#pragma unroll
    for (int k = 0; k < 9; k++) { vals[k] = __expf(vals[k] - m); es += vals[k]; }
    float ei = 1.0f / es;

    size_t pix = (size_t)i * WW + j;
    size_t base_o = (size_t)b * 18 * HWSZ + pix;
#pragma unroll
    for (int ch = 0; ch < 18; ch++) {
        float v;
        if (ch < 8) v = own[ch];
        else if (ch < 10) v = 0.f;
        else v = own[ch - 2];
        out[base_o + (size_t)ch * HWSZ] = v;
    }
    float* aff_out = out + (size_t)BB * 18 * HWSZ;
    size_t base_a = (size_t)b * 9 * HWSZ + pix;
#pragma unroll
    for (int k = 0; k < 9; k++)
        aff_out[base_a + (size_t)k * HWSZ] = vals[k] * ei;
}

// ---------------------------------------------------------------------------
extern "C" void kernel_launch(void* const* d_in, const int* in_sizes, int n_in,
                              void* d_out, int out_size, void* d_ws, size_t ws_size,
                              hipStream_t stream) {
    const void* guidance = d_in[0];
    const void* gtconf   = d_in[1];
    const void* tgt      = d_in[2];
    const void* conv_w   = d_in[3];
    const void* conv_b   = d_in[4];
    const void* asc      = d_in[5];

    // ws layout (bytes):
    //   oa : BB*HW*24 fp32          = 29,491,200
    //   fea: BB*8*HW fp32           =  9,830,400
    //   gT : BB*HW*64 bf16          = 39,321,600
    //   Bp : 18*32*32 bf16          =     36,864
    float* oa  = (float*)d_ws;
    float* fea = oa + (size_t)BB * HWSZ * NCO;
    unsigned short* gTu = (unsigned short*)(fea + (size_t)BB * 8 * HWSZ);
    unsigned short* Bpu = gTu + (size_t)BB * HWSZ * 64;
    const size_t ws_needed = (size_t)(29491200 + 9830400 + 39321600 + 36864);
    float* out = (float*)d_out;

    int n_up = BB * 8 * HWSZ;
    upsample_kernel<<<(n_up + 255) / 256, 256, 0, stream>>>(tgt, asc, fea);

    if (ws_size >= ws_needed) {
        dim3 pgrid(WW / 64, HH, BB);
        prep_guidance<<<pgrid, 256, 0, stream>>>(guidance, asc, gTu);
        prep_weights<<<1, 256, 0, stream>>>(conv_w, asc, Bpu);
        dim3 cgrid(WW / 64, HH, BB);
        conv_mfma_kernel<<<cgrid, 256, 0, stream>>>(gTu, Bpu, conv_b, asc, oa);
    } else {
        dim3 cgrid(WW / 16, HH / 16, BB);
        conv_fallback<<<cgrid, 256, 0, stream>>>(guidance, conv_w, conv_b, asc, oa);
    }

    int n_fin = BB * HWSZ;
    final_kernel<<<(n_fin + 255) / 256, 256, 0, stream>>>(oa, fea, gtconf, asc, out);
}

// Round 8
// 405.626 us; speedup vs baseline: 1.9945x; 1.0187x over previous
//
#include <hip/hip_runtime.h>
#include <hip/hip_bf16.h>

typedef __hip_bfloat16 bf16;
typedef __bf16 bf16x8 __attribute__((ext_vector_type(8)));
typedef float f32x4 __attribute__((ext_vector_type(4)));

#define BB 4
#define HH 240
#define WW 320
#define CG 64
#define NCO 24
#define HWSZ (HH*WW)

__device__ __forceinline__ float ldF(const void* __restrict__ p, long i, int isbf) {
    if (isbf) return __bfloat162float(((const bf16*)p)[i]);
    return ((const float*)p)[i];
}

__device__ __forceinline__ int detect_bf16(const void* asc) {
    // aff_scale_const == 4.0f: fp32 LE low u16 = 0x0000, bf16 = 0x4080.
    return ((const unsigned short*)asc)[0] != 0;
}

__device__ __forceinline__ unsigned short f2bfbits(float v) {
    bf16 h = __float2bfloat16(v);
    return *(unsigned short*)&h;
}

// ---------------------------------------------------------------------------
// Kernel 1: bilinear 2x upsample -> fp32 ws [b][c][i][j]
// ---------------------------------------------------------------------------
__global__ __launch_bounds__(256) void upsample_kernel(const void* __restrict__ tin,
                                                       const void* __restrict__ asc,
                                                       float* __restrict__ fea) {
    int isbf = detect_bf16(asc);
    int idx = blockIdx.x * 256 + threadIdx.x;
    if (idx >= BB * 8 * HWSZ) return;
    int j = idx % WW;
    int rest = idx / WW;
    int i = rest % HH;
    int bc = rest / HH;
    float sy = 0.5f * (float)i - 0.25f;
    float sx = 0.5f * (float)j - 0.25f;
    float y0f = floorf(sy), x0f = floorf(sx);
    float wy = sy - y0f, wx = sx - x0f;
    int y0 = (int)y0f, x0 = (int)x0f;
    int y0c = min(max(y0, 0), 119), y1c = min(max(y0 + 1, 0), 119);
    int x0c = min(max(x0, 0), 159), x1c = min(max(x0 + 1, 0), 159);
    long base = (long)bc * 120 * 160;
    float v00 = ldF(tin, base + y0c * 160 + x0c, isbf);
    float v01 = ldF(tin, base + y0c * 160 + x1c, isbf);
    float v10 = ldF(tin, base + y1c * 160 + x0c, isbf);
    float v11 = ldF(tin, base + y1c * 160 + x1c, isbf);
    fea[idx] = (1.f - wy) * ((1.f - wx) * v00 + wx * v01)
             + wy * ((1.f - wx) * v10 + wx * v11);
}

// ---------------------------------------------------------------------------
// Prep A: guidance NCHW -> channels-last bf16 gT[b][y][x][ci] via LDS transpose
// ---------------------------------------------------------------------------
__global__ __launch_bounds__(256) void prep_guidance(const void* __restrict__ g,
                                                     const void* __restrict__ asc,
                                                     unsigned short* __restrict__ gTu) {
    int isbf = detect_bf16(asc);
    int x0 = blockIdx.x * 64;
    int y  = blockIdx.y;
    int b  = blockIdx.z;
    __shared__ unsigned short sh[64][66];
    int tid = threadIdx.x;
#pragma unroll
    for (int it = 0; it < 16; it++) {
        int idx = it * 256 + tid;
        int ci = idx >> 6;
        int xg = idx & 63;
        float v = ldF(g, ((long)(b * CG + ci) * HH + y) * WW + x0 + xg, isbf);
        sh[xg][ci] = f2bfbits(v);
    }
    __syncthreads();
#pragma unroll
    for (int it = 0; it < 16; it++) {
        int idx = it * 256 + tid;
        int xg = idx >> 6;
        int ci = idx & 63;
        gTu[((((long)b * HH + y) * WW + x0 + xg) << 6) + ci] = sh[xg][ci];
    }
}

// ---------------------------------------------------------------------------
// Prep B: weights -> MFMA B-fragment layout Bp[t][n(32, 24 real)][k'(32)] bf16
// ---------------------------------------------------------------------------
__global__ __launch_bounds__(256) void prep_weights(const void* __restrict__ w,
                                                    const void* __restrict__ asc,
                                                    unsigned short* __restrict__ Bpu) {
    int isbf = detect_bf16(asc);
    for (int idx = threadIdx.x; idx < 18 * 32 * 32; idx += 256) {
        int t = idx >> 10;
        int r = idx & 1023;
        int n = r >> 5;
        int k = r & 31;
        int tap = t >> 1;
        int ch = t & 1;
        float v = 0.f;
        if (n < NCO)
            v = ldF(w, ((long)n * CG + ch * 32 + k) * 9 + tap, isbf);
        Bpu[idx] = f2bfbits(v);
    }
}

// ---------------------------------------------------------------------------
// Kernel 2 (MFMA): im2col GEMM conv. One wave = 16 px x 24(pad 32) co, K=576.
// ---------------------------------------------------------------------------
__global__ __launch_bounds__(256) void conv_mfma_kernel(const unsigned short* __restrict__ gTu,
                                                        const unsigned short* __restrict__ Bpu,
                                                        const void* __restrict__ bias,
                                                        const void* __restrict__ asc,
                                                        float* __restrict__ oa) {
    int isbf = detect_bf16(asc);
    int y  = blockIdx.y;
    int b  = blockIdx.z;
    int wid  = threadIdx.x >> 6;
    int lane = threadIdx.x & 63;
    int m = lane & 15, quad = lane >> 4;
    int x0 = blockIdx.x * 64 + wid * 16;

    f32x4 acc0 = {0.f, 0.f, 0.f, 0.f};
    f32x4 acc1 = {0.f, 0.f, 0.f, 0.f};

    for (int tap = 0; tap < 9; tap++) {
        int yy = y + tap / 3 - 1;
        if (yy < 0 || yy >= HH) continue;          // wave-uniform skip
        int xx = x0 + m + (tap % 3) - 1;
        bool xok = (xx >= 0) && (xx < WW);
        int xcl = min(max(xx, 0), WW - 1);
        long abase = (((long)b * HH + yy) * WW + xcl) * 64;
#pragma unroll
        for (int ch = 0; ch < 2; ch++) {
            int t = tap * 2 + ch;
            int4 ai = *(const int4*)(gTu + abase + ch * 32 + quad * 8);
            if (!xok) { ai.x = 0; ai.y = 0; ai.z = 0; ai.w = 0; }
            bf16x8 af = __builtin_bit_cast(bf16x8, ai);
            int4 b0i = *(const int4*)(Bpu + ((t * 32 + m) * 32 + quad * 8));
            int4 b1i = *(const int4*)(Bpu + ((t * 32 + 16 + m) * 32 + quad * 8));
            bf16x8 bf0 = __builtin_bit_cast(bf16x8, b0i);
            bf16x8 bf1 = __builtin_bit_cast(bf16x8, b1i);
            acc0 = __builtin_amdgcn_mfma_f32_16x16x32_bf16(af, bf0, acc0, 0, 0, 0);
            acc1 = __builtin_amdgcn_mfma_f32_16x16x32_bf16(af, bf1, acc1, 0, 0, 0);
        }
    }

    int n = lane & 15;
    float bias0 = ldF(bias, n, isbf);
    float bias1 = (n < 8) ? ldF(bias, 16 + n, isbf) : 0.f;
#pragma unroll
    for (int r = 0; r < 4; r++) {
        int px = x0 + quad * 4 + r;
        float* dst = &oa[(((size_t)b * HH + y) * WW + px) * NCO];
        dst[n] = acc0[r] + bias0;
        if (n < 8) dst[16 + n] = acc1[r] + bias1;
    }
}

// ---------------------------------------------------------------------------
// Fallback scalar conv (only if ws too small).
// ---------------------------------------------------------------------------
__global__ __launch_bounds__(256, 4) void conv_fallback(const void* __restrict__ g,
                                                        const void* __restrict__ w,
                                                        const void* __restrict__ bias,
                                                        const void* __restrict__ asc,
                                                        float* __restrict__ oa) {
    int isbf = detect_bf16(asc);
    const int b = blockIdx.z;
    const int i0 = blockIdx.y * 16;
    const int j0 = blockIdx.x * 16;
    const int tx = threadIdx.x & 15;
    const int ty = threadIdx.x >> 4;

    __shared__ float gl[8][18][20];
    __shared__ float wl[8][NCO][10];

    float acc[NCO];
#pragma unroll
    for (int c = 0; c < NCO; c++) acc[c] = ldF(bias, c, isbf);

    for (int ci0 = 0; ci0 < CG; ci0 += 8) {
        __syncthreads();
        for (int idx = threadIdx.x; idx < 8 * NCO * 9; idx += 256) {
            int t = idx % 9;
            int rest = idx / 9;
            int cc = rest & 7;
            int co = rest >> 3;
            wl[cc][co][t] = ldF(w, (long)(co * CG + ci0 + cc) * 9 + t, isbf);
        }
        for (int idx = threadIdx.x; idx < 8 * 18 * 18; idx += 256) {
            int cc = idx / 324;
            int rem = idx - cc * 324;
            int r = rem / 18;
            int c2 = rem - r * 18;
            int gi = i0 - 1 + r;
            int gj = j0 - 1 + c2;
            float v = 0.f;
            if (gi >= 0 && gi < HH && gj >= 0 && gj < WW)
                v = ldF(g, ((long)(b * CG + ci0 + cc) * HH + gi) * WW + gj, isbf);
            gl[cc][r][c2] = v;
        }
        __syncthreads();
#pragma unroll
        for (int cc = 0; cc < 8; cc++) {
            float ga[9];
#pragma unroll
            for (int dy = 0; dy < 3; dy++)
#pragma unroll
                for (int dx = 0; dx < 3; dx++)
                    ga[dy * 3 + dx] = gl[cc][ty + dy][tx + dx];
#pragma unroll 4
            for (int co = 0; co < NCO; co++) {
                float s = 0.f;
#pragma unroll
                for (int t = 0; t < 9; t++)
                    s += wl[cc][co][t] * ga[t];
                acc[co] += s;
            }
        }
    }
    int i = i0 + ty, j = j0 + tx;
    float4* p = (float4*)&oa[(((size_t)b * HH + i) * WW + j) * NCO];
#pragma unroll
    for (int q = 0; q < 6; q++)
        p[q] = make_float4(acc[4 * q], acc[4 * q + 1], acc[4 * q + 2], acc[4 * q + 3]);
}

// ---------------------------------------------------------------------------
// Branchless bilinear, zero outside: clamp indices, mask corner weights.
// Exactly reference _bilinear_zeros (img*valid per corner).
// ---------------------------------------------------------------------------
__device__ __forceinline__ float bil_zero_f32(const float* __restrict__ img,
                                              float x, float y) {
    float x0f = floorf(x), y0f = floorf(y);
    float wx = x - x0f, wy = y - y0f;
    int x0 = (int)x0f, y0 = (int)y0f;
    int x0c = min(max(x0, 0), WW - 1), x1c = min(max(x0 + 1, 0), WW - 1);
    int y0c = min(max(y0, 0), HH - 1), y1c = min(max(y0 + 1, 0), HH - 1);
    float mx0 = (x0 == x0c) ? 1.f : 0.f;
    float mx1 = (x0 + 1 == x1c) ? 1.f : 0.f;
    float my0 = (y0 == y0c) ? 1.f : 0.f;
    float my1 = (y0 + 1 == y1c) ? 1.f : 0.f;
    const float* r0 = img + (size_t)y0c * WW;
    const float* r1 = img + (size_t)y1c * WW;
    float v00 = r0[x0c], v01 = r0[x1c], v10 = r1[x0c], v11 = r1[x1c];
    return my0 * (1.f - wy) * (mx0 * (1.f - wx) * v00 + mx1 * wx * v01)
         + my1 * wy * (mx0 * (1.f - wx) * v10 + mx1 * wx * v11);
}

__device__ __forceinline__ float bil_zero_poly(const void* __restrict__ img, long base,
                                               float x, float y, int isbf) {
    float x0f = floorf(x), y0f = floorf(y);
    float wx = x - x0f, wy = y - y0f;
    int x0 = (int)x0f, y0 = (int)y0f;
    int x0c = min(max(x0, 0), WW - 1), x1c = min(max(x0 + 1, 0), WW - 1);
    int y0c = min(max(y0, 0), HH - 1), y1c = min(max(y0 + 1, 0), HH - 1);
    float mx0 = (x0 == x0c) ? 1.f : 0.f;
    float mx1 = (x0 + 1 == x1c) ? 1.f : 0.f;
    float my0 = (y0 == y0c) ? 1.f : 0.f;
    float my1 = (y0 + 1 == y1c) ? 1.f : 0.f;
    long r0 = base + (long)y0c * WW;
    long r1 = base + (long)y1c * WW;
    float v00 = ldF(img, r0 + x0c, isbf), v01 = ldF(img, r0 + x1c, isbf);
    float v10 = ldF(img, r1 + x0c, isbf), v11 = ldF(img, r1 + x1c, isbf);
    return my0 * (1.f - wy) * (mx0 * (1.f - wx) * v00 + mx1 * wx * v01)
         + my1 * wy * (mx0 * (1.f - wx) * v10 + mx1 * wx * v11);
}

// ---------------------------------------------------------------------------
// Kernel 3: scrambled cosine-affinity gather + conf + TGASS + softmax + writes.
//   cos_w[b,c,i,j] = sum_{n<8} fea_up[b,n,i,j] * bil(fea_up[b, i/30], px, py)
//   source grid pixel (pi,qj) = ((i%30)*8 + j/40, (j%40)*8 + n)
//   px = oa[pi,qj,2c]+add, py = oa[pi,qj,2c+1]+add, add = (c<4 ? pi : qj)
//
// R7 post-mortem: full n-loop unroll -> 256 VGPR -> 10% occupancy,
// latency-bound at 167us. R8: unroll 1 + launch_bounds(256,4) caps VGPR
// at 128 -> 4 blocks/CU; branchless bilinear removes exec-mask churn.
// ---------------------------------------------------------------------------
__global__ __launch_bounds__(256, 4) void final_kernel(const float* __restrict__ oa,
                                                       const float* __restrict__ fea,
                                                       const void* __restrict__ conf_in,
                                                       const void* __restrict__ asc_p,
                                                       float* __restrict__ out) {
    int isbf = detect_bf16(asc_p);
    int idx = blockIdx.x * 256 + threadIdx.x;
    if (idx >= BB * HWSZ) return;
    int j = idx % WW;
    int rest = idx / WW;
    int i = rest % HH;
    int b = rest / HH;

    const float* feaB = fea + (size_t)b * 8 * HWSZ;
    float f[8];
#pragma unroll
    for (int n = 0; n < 8; n++)
        f[n] = feaB[(size_t)n * HWSZ + (size_t)i * WW + j];

    int c_img = i / 30;
    int pi = (i % 30) * 8 + j / 40;
    int pj0 = (j % 40) * 8;
    const float* feaC = feaB + (size_t)c_img * HWSZ;

    float cos_acc[8];
#pragma unroll
    for (int c = 0; c < 8; c++) cos_acc[c] = 0.f;

#pragma unroll 1
    for (int n = 0; n < 8; n++) {
        int qj = pj0 + n;
        const float4* oq = (const float4*)&oa[(((size_t)b * HH + pi) * WW + qj) * NCO];
        float4 o0 = oq[0], o1 = oq[1], o2 = oq[2], o3 = oq[3];
        float off[16] = {o0.x, o0.y, o0.z, o0.w, o1.x, o1.y, o1.z, o1.w,
                         o2.x, o2.y, o2.z, o2.w, o3.x, o3.y, o3.z, o3.w};
        float fn = f[n];
#pragma unroll
        for (int c = 0; c < 8; c++) {
            float add = (c < 4) ? (float)pi : (float)qj;
            float px = off[2 * c] + add;
            float py = off[2 * c + 1] + add;
            cos_acc[c] += fn * bil_zero_f32(feaC, px, py);
        }
    }

    const float4* op = (const float4*)&oa[(((size_t)b * HH + i) * WW + j) * NCO];
    float own[24];
#pragma unroll
    for (int q = 0; q < 6; q++) {
        float4 v = op[q];
        own[4 * q] = v.x; own[4 * q + 1] = v.y; own[4 * q + 2] = v.z; own[4 * q + 3] = v.w;
    }

    float asc = ldF(asc_p, 0, isbf) + 1e-8f;
    long cbase = (long)b * HWSZ;

    float a[8];
    float ssum = 0.f;
#pragma unroll
    for (int c = 0; c < 8; c++) {
        float v = own[16 + c] * cos_acc[c];
        v = tanhf(v) / asc;
        float py2 = own[2 * c] + (float)i;
        float px2 = own[2 * c + 1] + (float)j;
        float cf = bil_zero_poly(conf_in, cbase, px2, py2, isbf);
        v *= cf;
        a[c] = v;
        ssum += fabsf(v);
    }
    ssum += 1e-4f;
    ssum = fmaxf(ssum, 1.0f);
    float inv = 1.0f / ssum;
    float asum = 0.f;
#pragma unroll
    for (int c = 0; c < 8; c++) { a[c] *= inv; asum += a[c]; }
    float aref = 1.0f - asum;

    float vals[9];
#pragma unroll
    for (int c = 0; c < 4; c++) vals[c] = a[c];
    vals[4] = aref;
#pragma unroll
    for (int c = 4; c < 8; c++) vals[c + 1] = a[c];
    float m = vals[0];
#pragma unroll
    for (int k = 1; k < 9; k++) m = fmaxf(m, vals[k]);
    float es = 0.f;
#pragma unroll
    for (int k = 0; k < 9; k++) { vals[k] = __expf(vals[k] - m); es += vals[k]; }
    float ei = 1.0f / es;

    size_t pix = (size_t)i * WW + j;
    size_t base_o = (size_t)b * 18 * HWSZ + pix;
#pragma unroll
    for (int ch = 0; ch < 18; ch++) {
        float v;
        if (ch < 8) v = own[ch];
        else if (ch < 10) v = 0.f;
        else v = own[ch - 2];
        out[base_o + (size_t)ch * HWSZ] = v;
    }
    float* aff_out = out + (size_t)BB * 18 * HWSZ;
    size_t base_a = (size_t)b * 9 * HWSZ + pix;
#pragma unroll
    for (int k = 0; k < 9; k++)
        aff_out[base_a + (size_t)k * HWSZ] = vals[k] * ei;
}

// ---------------------------------------------------------------------------
extern "C" void kernel_launch(void* const* d_in, const int* in_sizes, int n_in,
                              void* d_out, int out_size, void* d_ws, size_t ws_size,
                              hipStream_t stream) {
    const void* guidance = d_in[0];
    const void* gtconf   = d_in[1];
    const void* tgt      = d_in[2];
    const void* conv_w   = d_in[3];
    const void* conv_b   = d_in[4];
    const void* asc      = d_in[5];

    float* oa  = (float*)d_ws;
    float* fea = oa + (size_t)BB * HWSZ * NCO;
    unsigned short* gTu = (unsigned short*)(fea + (size_t)BB * 8 * HWSZ);
    unsigned short* Bpu = gTu + (size_t)BB * HWSZ * 64;
    const size_t ws_needed = (size_t)(29491200 + 9830400 + 39321600 + 36864);
    float* out = (float*)d_out;

    int n_up = BB * 8 * HWSZ;
    upsample_kernel<<<(n_up + 255) / 256, 256, 0, stream>>>(tgt, asc, fea);

    if (ws_size >= ws_needed) {
        dim3 pgrid(WW / 64, HH, BB);
        prep_guidance<<<pgrid, 256, 0, stream>>>(guidance, asc, gTu);
        prep_weights<<<1, 256, 0, stream>>>(conv_w, asc, Bpu);
        dim3 cgrid(WW / 64, HH, BB);
        conv_mfma_kernel<<<cgrid, 256, 0, stream>>>(gTu, Bpu, conv_b, asc, oa);
    } else {
        dim3 cgrid(WW / 16, HH / 16, BB);
        conv_fallback<<<cgrid, 256, 0, stream>>>(guidance, conv_w, conv_b, asc, oa);
    }

    int n_fin = BB * HWSZ;
    final_kernel<<<(n_fin + 255) / 256, 256, 0, stream>>>(oa, fea, gtconf, asc, out);
}